// Round 1
// baseline (19.746 us; speedup 1.0000x reference)
//
#include <hip/hip_runtime.h>
#include <math.h>

#define BB 4
#define PP 16384
#define GG 512
#define HH 512
#define WW 512
#define CAP 160

// Workspace layout (bytes):
//   counts : [B][G] int      at 0                  (8 KB)
//   labels : [B][P] int      at 8192               (256 KB)
//   buckets: [B][G][CAP] int at 8192 + B*P*4       (1.31 MB)
#define WS_COUNTS(ws)  ((int*)(ws))
#define WS_LABELS(ws)  ((int*)((char*)(ws) + BB*GG*4))
#define WS_BUCKETS(ws) ((int*)((char*)(ws) + BB*GG*4 + BB*PP*4))

__device__ __forceinline__ float distf(float px, float py, float gx, float gy) {
#pragma clang fp contract(off)
    float dx = px - gx;
    float dy = py - gy;
    float a = dx * dx;
    float c = dy * dy;
    return sqrtf(a + c);   // matches XLA: separate mul/add/sqrt, no FMA contraction
}

// Zero bucket counts (ws is NOT re-poisoned between replays) and emit tgt = arange(G).
__global__ void k_init(int* counts, float* out_tgt) {
    int t = blockIdx.x * blockDim.x + threadIdx.x;
    if (t < BB * GG) {
        counts[t] = 0;
        out_tgt[t] = (float)(t % GG);
    }
}

// Per point: rounded+clipped pixel label; scatter point index into its label's bucket.
__global__ void k_label(const float* __restrict__ pred, const int* __restrict__ lm,
                        int* __restrict__ counts, int* __restrict__ labels,
                        int* __restrict__ buckets) {
    int t = blockIdx.x * blockDim.x + threadIdx.x;   // [0, B*P)
    if (t >= BB * PP) return;
    int b = t / PP;
    float px = pred[2 * t + 0];
    float py = pred[2 * t + 1];
    int x = (int)rintf(px);  x = min(max(x, 0), WW - 1);   // round half-to-even, like jnp.round
    int y = (int)rintf(py);  y = min(max(y, 0), HH - 1);
    int lab = lm[(b * HH + y) * WW + x];
    labels[t] = lab;
    if (lab > 0) {
        int g = lab - 1;
        int slot = atomicAdd(&counts[b * GG + g], 1);
        if (slot < CAP) buckets[(b * GG + g) * CAP + slot] = t - b * PP;
    }
}

// One wave (64 lanes) per (b, g): min-distance over candidates, tie-break lowest index.
__global__ void k_match(const float* __restrict__ pred, const float* __restrict__ gt,
                        const int* __restrict__ counts, const int* __restrict__ labels,
                        const int* __restrict__ buckets, float* __restrict__ out) {
    int wv   = blockIdx.x * (blockDim.x >> 6) + (threadIdx.x >> 6);
    int lane = threadIdx.x & 63;
    if (wv >= BB * GG) return;
    int b = wv / GG, g = wv % GG;

    float gx = gt[2 * (b * GG + g) + 0];
    float gy = gt[2 * (b * GG + g) + 1];
    int cnt = counts[b * GG + g];

    float bd = INFINITY;
    int   bi = 0x7fffffff;

    if (cnt == 0) {
        // no point inside mask g: argmin over ALL points
        for (int p = lane; p < PP; p += 64) {
            float px = pred[2 * (b * PP + p) + 0];
            float py = pred[2 * (b * PP + p) + 1];
            float d = distf(px, py, gx, gy);
            if (d < bd || (d == bd && p < bi)) { bd = d; bi = p; }
        }
    } else if (cnt <= CAP) {
        for (int e = lane; e < cnt; e += 64) {
            int p = buckets[(b * GG + g) * CAP + e];
            float px = pred[2 * (b * PP + p) + 0];
            float py = pred[2 * (b * PP + p) + 1];
            float d = distf(px, py, gx, gy);
            if (d < bd || (d == bd && p < bi)) { bd = d; bi = p; }
        }
    } else {
        // bucket overflow (statistically ~impossible at CAP=160, mean 32): exact re-filter
        for (int p = lane; p < PP; p += 64) {
            if (labels[b * PP + p] == g + 1) {
                float px = pred[2 * (b * PP + p) + 0];
                float py = pred[2 * (b * PP + p) + 1];
                float d = distf(px, py, gx, gy);
                if (d < bd || (d == bd && p < bi)) { bd = d; bi = p; }
            }
        }
    }

    // wave butterfly reduce: (min d, then min original index) — order-invariant
    for (int off = 32; off > 0; off >>= 1) {
        float od = __shfl_xor(bd, off, 64);
        int   oi = __shfl_xor(bi, off, 64);
        if (od < bd || (od == bd && oi < bi)) { bd = od; bi = oi; }
    }

    if (lane == 0) {
        out[b * GG + g]               = (float)bi;  // src_idx
        out[2 * BB * GG + b * GG + g] = bd;         // costs  (tgt written by k_init)
    }
}

extern "C" void kernel_launch(void* const* d_in, const int* in_sizes, int n_in,
                              void* d_out, int out_size, void* d_ws, size_t ws_size,
                              hipStream_t stream) {
    const float* pred = (const float*)d_in[0];
    const float* gt   = (const float*)d_in[1];
    const int*   lm   = (const int*)d_in[2];
    float* out = (float*)d_out;

    int* counts  = WS_COUNTS(d_ws);
    int* labels  = WS_LABELS(d_ws);
    int* buckets = WS_BUCKETS(d_ws);

    // 1) zero counts + write tgt = arange(G)
    k_init<<<(BB * GG + 255) / 256, 256, 0, stream>>>(counts, out + BB * GG);

    // 2) label each point, scatter into per-(b,label) buckets
    k_label<<<(BB * PP + 255) / 256, 256, 0, stream>>>(pred, lm, counts, labels, buckets);

    // 3) one wave per (b,g): nearest candidate (or fallback) with exact JAX-matching math
    k_match<<<(BB * GG * 64 + 255) / 256, 256, 0, stream>>>(pred, gt, counts, labels, buckets, out);
}